// Round 4
// baseline (167.572 us; speedup 1.0000x reference)
//
#include <hip/hip_runtime.h>

#define NBLK 2048
#define NTHR 256

typedef float f32x4 __attribute__((ext_vector_type(4)));

// Single fused kernel: 4-way dot-product partial reduction + last-block finalize.
// input  : (N, 2) fp32 row-major (interleaved columns)
// weight : (4, N) fp32 row-major
// out[0]=w0.in[:,0]  out[1]=w1.in[:,0]  out[2]=w2.in[:,1]  out[3]=w3.in[:,1]
//
// d_ws layout: [0 .. NBLK*4) floats = partials (32 KB); counter at byte 32768.
//
// __launch_bounds__(256, 8): R3 lesson — without the waves/EU target the
// fused epilogue tipped regalloc to VGPR=24, serializing the 6 loads
// (1 outstanding load/wave -> measured 1.03 TB/s, latency-bound). Pinning
// 8 waves/EU caps VGPR at 64 and removes any incentive to squeeze below it,
// keeping all 6 loads grouped in flight (R2's 6.34 TB/s pattern).
__global__ __launch_bounds__(NTHR, 8) void motor_fused(
    const float* __restrict__ inp,
    const float* __restrict__ w,
    float* __restrict__ partial,
    unsigned int* __restrict__ counter,   // zeroed by hipMemsetAsync each call
    float* __restrict__ out,
    int n)  // n = IN_FEATURES
{
    const f32x4* __restrict__ in4 = (const f32x4*)inp;  // each f32x4 = 2 rows x 2 cols
    const f32x4* __restrict__ w0 = (const f32x4*)(w);
    const f32x4* __restrict__ w1 = (const f32x4*)(w + (size_t)n);
    const f32x4* __restrict__ w2 = (const f32x4*)(w + 2 * (size_t)n);
    const f32x4* __restrict__ w3 = (const f32x4*)(w + 3 * (size_t)n);

    float a0 = 0.f, a1 = 0.f, a2 = 0.f, a3 = 0.f;
    const int n4 = n >> 2;                      // f32x4 count per weight row
    const int stride = gridDim.x * blockDim.x;

    for (int i = blockIdx.x * NTHR + threadIdx.x; i < n4; i += stride) {
        // weight streams: single-use, each 64B line fully consumed by one
        // instruction's lanes -> non-temporal (evict-first). [R2: 77.4->68.4us]
        f32x4 wa = __builtin_nontemporal_load(w0 + i);
        f32x4 wb = __builtin_nontemporal_load(w1 + i);
        f32x4 wc = __builtin_nontemporal_load(w2 + i);
        f32x4 wd = __builtin_nontemporal_load(w3 + i);
        // input stream: two instructions share each 64B line -> cached loads.
        f32x4 p = in4[2 * i];       // rows 4i,4i+1 : (c0,c1,c0,c1)
        f32x4 q = in4[2 * i + 1];   // rows 4i+2,4i+3

        a0 += wa.x * p.x + wa.y * p.z + wa.z * q.x + wa.w * q.z;
        a1 += wb.x * p.x + wb.y * p.z + wb.z * q.x + wb.w * q.z;
        a2 += wc.x * p.y + wc.y * p.w + wc.z * q.y + wc.w * q.w;
        a3 += wd.x * p.y + wd.y * p.w + wd.z * q.y + wd.w * q.w;
    }

    // wave64 butterfly reduce
    for (int off = 32; off > 0; off >>= 1) {
        a0 += __shfl_down(a0, off);
        a1 += __shfl_down(a1, off);
        a2 += __shfl_down(a2, off);
        a3 += __shfl_down(a3, off);
    }

    __shared__ float s[NTHR / 64][4];
    __shared__ int is_last;
    const int wave = threadIdx.x >> 6;
    if ((threadIdx.x & 63) == 0) {
        s[wave][0] = a0; s[wave][1] = a1; s[wave][2] = a2; s[wave][3] = a3;
    }
    __syncthreads();
    if (threadIdx.x == 0) {
        float r0 = 0.f, r1 = 0.f, r2 = 0.f, r3 = 0.f;
        for (int wv = 0; wv < NTHR / 64; ++wv) {
            r0 += s[wv][0]; r1 += s[wv][1]; r2 += s[wv][2]; r3 += s[wv][3];
        }
        float4* p4 = (float4*)(partial + 4 * (size_t)blockIdx.x);
        *p4 = make_float4(r0, r1, r2, r3);
        __threadfence();  // release: partial visible device-wide before counter bump
        unsigned int prev = atomicAdd(counter, 1u);
        is_last = (prev == (unsigned int)(gridDim.x - 1)) ? 1 : 0;
    }
    __syncthreads();
    if (!is_last) return;

    // Last block: deterministic fixed-order final reduce of NBLK x 4 partials.
    __threadfence();  // acquire: see all blocks' partials
    float b0 = 0.f, b1 = 0.f, b2 = 0.f, b3 = 0.f;
    for (int b = threadIdx.x; b < NBLK; b += NTHR) {
        const float4 v = *(const float4*)(partial + 4 * (size_t)b);
        b0 += v.x; b1 += v.y; b2 += v.z; b3 += v.w;
    }
    for (int off = 32; off > 0; off >>= 1) {
        b0 += __shfl_down(b0, off);
        b1 += __shfl_down(b1, off);
        b2 += __shfl_down(b2, off);
        b3 += __shfl_down(b3, off);
    }
    __syncthreads();  // LDS buffer s[][] reuse
    if ((threadIdx.x & 63) == 0) {
        s[wave][0] = b0; s[wave][1] = b1; s[wave][2] = b2; s[wave][3] = b3;
    }
    __syncthreads();
    if (threadIdx.x == 0) {
        float r0 = 0.f, r1 = 0.f, r2 = 0.f, r3 = 0.f;
        for (int wv = 0; wv < NTHR / 64; ++wv) {
            r0 += s[wv][0]; r1 += s[wv][1]; r2 += s[wv][2]; r3 += s[wv][3];
        }
        out[0] = r0; out[1] = r1; out[2] = r2; out[3] = r3;
    }
}

extern "C" void kernel_launch(void* const* d_in, const int* in_sizes, int n_in,
                              void* d_out, int out_size, void* d_ws, size_t ws_size,
                              hipStream_t stream) {
    const float* inp = (const float*)d_in[0];   // (N,2) fp32
    const float* w   = (const float*)d_in[1];   // (4,N) fp32
    float* out = (float*)d_out;
    float* partial = (float*)d_ws;                              // NBLK*4 floats = 32 KB
    unsigned int* counter = (unsigned int*)((char*)d_ws + NBLK * 4 * sizeof(float));

    const int n = in_sizes[0] / 2;              // IN_FEATURES

    // Reset last-block counter each call (handles 0xAA poison; capture-safe).
    hipMemsetAsync(counter, 0, sizeof(unsigned int), stream);
    motor_fused<<<NBLK, NTHR, 0, stream>>>(inp, w, partial, counter, out, n);
}

// Round 6
// 69.142 us; speedup vs baseline: 2.4236x; 2.4236x over previous
//
#include <hip/hip_runtime.h>

#define NBLK 2048
#define NTHR 256

typedef float f32x4 __attribute__((ext_vector_type(4)));

// Two-kernel structure (R2: 68.4us). R3/R4 lesson: last-block-atomic fusion
// costs ~130us (2048 simultaneous device-scope fences + same-line atomics).
// R5 lesson: the partial hand-off between the two kernels MUST be device-scope
// (agent) atomics — plain stores/loads flaked under graph replay because the
// partial buffer stays dirty in per-XCD L2s (not cross-coherent) and the
// finalize block's XCD served stale poisoned lines (post-timing absmax 976).
//
// Kernel 1: fused 4-way dot-product partial reduction.
// input  : (N, 2) fp32 row-major (interleaved columns)
// weight : (4, N) fp32 row-major
// out[0]=w0.in[:,0]  out[1]=w1.in[:,0]  out[2]=w2.in[:,1]  out[3]=w3.in[:,1]
__global__ __launch_bounds__(NTHR) void motor_partial(
    const float* __restrict__ inp,
    const float* __restrict__ w,
    float* __restrict__ partial,
    int n)  // n = IN_FEATURES
{
    const f32x4* __restrict__ in4 = (const f32x4*)inp;  // each f32x4 = 2 rows x 2 cols
    const f32x4* __restrict__ w0 = (const f32x4*)(w);
    const f32x4* __restrict__ w1 = (const f32x4*)(w + (size_t)n);
    const f32x4* __restrict__ w2 = (const f32x4*)(w + 2 * (size_t)n);
    const f32x4* __restrict__ w3 = (const f32x4*)(w + 3 * (size_t)n);

    float a0 = 0.f, a1 = 0.f, a2 = 0.f, a3 = 0.f;
    const int n4 = n >> 2;                      // f32x4 count per weight row
    const int stride = gridDim.x * blockDim.x;

    for (int i = blockIdx.x * NTHR + threadIdx.x; i < n4; i += stride) {
        // weight streams: single-use, each 64B line fully consumed by one
        // instruction's lanes -> non-temporal (evict-first). [R2: 77.4->68.4us]
        f32x4 wa = __builtin_nontemporal_load(w0 + i);
        f32x4 wb = __builtin_nontemporal_load(w1 + i);
        f32x4 wc = __builtin_nontemporal_load(w2 + i);
        f32x4 wd = __builtin_nontemporal_load(w3 + i);
        // input stream: two instructions share each 64B line -> cached loads.
        f32x4 p = in4[2 * i];       // rows 4i,4i+1 : (c0,c1,c0,c1)
        f32x4 q = in4[2 * i + 1];   // rows 4i+2,4i+3

        a0 += wa.x * p.x + wa.y * p.z + wa.z * q.x + wa.w * q.z;
        a1 += wb.x * p.x + wb.y * p.z + wb.z * q.x + wb.w * q.z;
        a2 += wc.x * p.y + wc.y * p.w + wc.z * q.y + wc.w * q.w;
        a3 += wd.x * p.y + wd.y * p.w + wd.z * q.y + wd.w * q.w;
    }

    // wave64 butterfly reduce
    for (int off = 32; off > 0; off >>= 1) {
        a0 += __shfl_down(a0, off);
        a1 += __shfl_down(a1, off);
        a2 += __shfl_down(a2, off);
        a3 += __shfl_down(a3, off);
    }

    __shared__ float s[NTHR / 64][4];
    const int wave = threadIdx.x >> 6;
    if ((threadIdx.x & 63) == 0) {
        s[wave][0] = a0; s[wave][1] = a1; s[wave][2] = a2; s[wave][3] = a3;
    }
    __syncthreads();
    if (threadIdx.x == 0) {
        float r0 = 0.f, r1 = 0.f, r2 = 0.f, r3 = 0.f;
        for (int wv = 0; wv < NTHR / 64; ++wv) {
            r0 += s[wv][0]; r1 += s[wv][1]; r2 += s[wv][2]; r3 += s[wv][3];
        }
        // Agent-scope stores: push partials past the per-XCD L2 to the device
        // coherence point so the finalize kernel (any XCD) reads fresh values.
        float* p4 = partial + 4 * (size_t)blockIdx.x;
        __hip_atomic_store(p4 + 0, r0, __ATOMIC_RELAXED, __HIP_MEMORY_SCOPE_AGENT);
        __hip_atomic_store(p4 + 1, r1, __ATOMIC_RELAXED, __HIP_MEMORY_SCOPE_AGENT);
        __hip_atomic_store(p4 + 2, r2, __ATOMIC_RELAXED, __HIP_MEMORY_SCOPE_AGENT);
        __hip_atomic_store(p4 + 3, r3, __ATOMIC_RELAXED, __HIP_MEMORY_SCOPE_AGENT);
    }
}

// Kernel 2: deterministic fixed-order final reduce of NBLK x 4 partials.
// Agent-scope loads bypass any stale locally-cached lines.
__global__ __launch_bounds__(NTHR) void motor_finalize(
    const float* __restrict__ partial,
    float* __restrict__ out,
    int nblk)
{
    float a0 = 0.f, a1 = 0.f, a2 = 0.f, a3 = 0.f;
    for (int b = threadIdx.x; b < nblk; b += NTHR) {
        const float* p4 = partial + 4 * (size_t)b;
        a0 += __hip_atomic_load(p4 + 0, __ATOMIC_RELAXED, __HIP_MEMORY_SCOPE_AGENT);
        a1 += __hip_atomic_load(p4 + 1, __ATOMIC_RELAXED, __HIP_MEMORY_SCOPE_AGENT);
        a2 += __hip_atomic_load(p4 + 2, __ATOMIC_RELAXED, __HIP_MEMORY_SCOPE_AGENT);
        a3 += __hip_atomic_load(p4 + 3, __ATOMIC_RELAXED, __HIP_MEMORY_SCOPE_AGENT);
    }
    for (int off = 32; off > 0; off >>= 1) {
        a0 += __shfl_down(a0, off);
        a1 += __shfl_down(a1, off);
        a2 += __shfl_down(a2, off);
        a3 += __shfl_down(a3, off);
    }
    __shared__ float s[NTHR / 64][4];
    const int wave = threadIdx.x >> 6;
    if ((threadIdx.x & 63) == 0) {
        s[wave][0] = a0; s[wave][1] = a1; s[wave][2] = a2; s[wave][3] = a3;
    }
    __syncthreads();
    if (threadIdx.x == 0) {
        float r0 = 0.f, r1 = 0.f, r2 = 0.f, r3 = 0.f;
        for (int wv = 0; wv < NTHR / 64; ++wv) {
            r0 += s[wv][0]; r1 += s[wv][1]; r2 += s[wv][2]; r3 += s[wv][3];
        }
        out[0] = r0; out[1] = r1; out[2] = r2; out[3] = r3;
    }
}

extern "C" void kernel_launch(void* const* d_in, const int* in_sizes, int n_in,
                              void* d_out, int out_size, void* d_ws, size_t ws_size,
                              hipStream_t stream) {
    const float* inp = (const float*)d_in[0];   // (N,2) fp32
    const float* w   = (const float*)d_in[1];   // (4,N) fp32
    float* out = (float*)d_out;
    float* partial = (float*)d_ws;              // NBLK*4 floats = 32 KB

    const int n = in_sizes[0] / 2;              // IN_FEATURES

    motor_partial<<<NBLK, NTHR, 0, stream>>>(inp, w, partial, n);
    motor_finalize<<<1, NTHR, 0, stream>>>(partial, out, NBLK);
}